// Round 1
// baseline (448.436 us; speedup 1.0000x reference)
//
#include <hip/hip_runtime.h>

// Problem constants
#define NH 12
#define NTOK 196
#define TT 32
#define KW 4
#define NI 25088            // k*n*t tokens per batch element
#define TSTRIDE 602112      // 4*12*196*64  : x flat stride for t+1 (same b,k)
// x flat index: ((B*12 + h)*196 + n)*64 + c ;  B = (b*32 + t)*4 + k

// ---------------------------------------------------------------------------
// K1: attn (fwd+bwd dot with pool weights) + write-through copy of c=16..63.
// Block 256 = 4 waves; each wave: one B, 4 consecutive n (16 lanes each = 64c).
__global__ __launch_bounds__(256) void k_attn(
    const float4* __restrict__ x4, const float4* __restrict__ wf4,
    const float4* __restrict__ wb4, float* __restrict__ attn,
    float4* __restrict__ out4)
{
  int B = blockIdx.y;
  int wave = threadIdx.x >> 6, lane = threadIdx.x & 63;
  int n = blockIdx.x * 16 + wave * 4 + (lane >> 4);
  int c4 = lane & 15;                 // float4 group: c = 4*c4
  bool nv = (n < NTOK);
  float accf = 0.f, accb = 0.f;
  #pragma unroll
  for (int h = 0; h < NH; h++) {
    float4 xv = make_float4(0.f, 0.f, 0.f, 0.f);
    int gi = ((B * NH + h) * NTOK + n) * 16 + c4;
    if (nv) xv = x4[gi];
    float4 wf = wf4[h * 16 + c4];
    float4 wb = wb4[h * 16 + c4];
    accf += xv.x * wf.x + xv.y * wf.y + xv.z * wf.z + xv.w * wf.w;
    accb += xv.x * wb.x + xv.y * wb.y + xv.z * wb.z + xv.w * wb.w;
    if (nv && c4 >= 4) out4[gi] = xv;   // pass-through channels 16..63
  }
  #pragma unroll
  for (int m = 1; m < 16; m <<= 1) {    // reduce within 16-lane (per-n) groups
    accf += __shfl_xor(accf, m);
    accb += __shfl_xor(accb, m);
  }
  if (nv && (lane & 15) == 0) {
    int b = B >> 7, t = (B >> 2) & 31, k = B & 3;
    int i = (k * NTOK + n) * TT + t;
    attn[(0 * 2 + b) * NI + i] = accf;  // prob = dir*2 + b
    attn[(1 * 2 + b) * NI + i] = accb;
  }
}

// ---------------------------------------------------------------------------
// K2: entmax-1.5 threshold by bisection over Sum max(0,z-tau)^2 = 1, then
// compact the support (index, weight) via atomic counter. One block per
// (dir,b) problem; 1024 threads x 25 values in registers.
__global__ __launch_bounds__(1024) void k_entmax_big(
    const float* __restrict__ attn, float* __restrict__ wgt,
    int* __restrict__ idxb, int* __restrict__ cnt)
{
  int p = blockIdx.x;
  const float* a = attn + p * NI;
  int tid = threadIdx.x;
  float v[25];
  float mx = -3.0e38f;
  #pragma unroll
  for (int r = 0; r < 25; r++) {
    int i = r * 1024 + tid;
    v[r] = (i < NI) ? a[i] : -3.0e38f;
    mx = fmaxf(mx, v[r]);
  }
  __shared__ float sred[16];
  __shared__ float sbc;
  int wv = tid >> 6;
  #pragma unroll
  for (int m = 1; m < 64; m <<= 1) mx = fmaxf(mx, __shfl_xor(mx, m));
  if ((tid & 63) == 0) sred[wv] = mx;
  __syncthreads();
  if (tid == 0) {
    float m2 = sred[0];
    for (int i2 = 1; i2 < 16; i2++) m2 = fmaxf(m2, sred[i2]);
    sbc = m2;
  }
  __syncthreads();
  float amax = sbc;
  #pragma unroll
  for (int r = 0; r < 25; r++) v[r] = 0.5f * (v[r] - amax);
  float lo = -1.f, hi = 0.f;
  for (int it = 0; it < 30; it++) {
    float mid = 0.5f * (lo + hi);
    float s = 0.f;
    #pragma unroll
    for (int r = 0; r < 25; r++) {
      float d = fmaxf(v[r] - mid, 0.f);
      s += d * d;
    }
    #pragma unroll
    for (int m = 1; m < 64; m <<= 1) s += __shfl_xor(s, m);
    if ((tid & 63) == 0) sred[wv] = s;
    __syncthreads();
    if (tid == 0) {
      float t2 = 0.f;
      for (int i2 = 0; i2 < 16; i2++) t2 += sred[i2];
      sbc = t2;
    }
    __syncthreads();
    if (sbc >= 1.f) lo = mid; else hi = mid;
  }
  float tau = 0.5f * (lo + hi);
  #pragma unroll
  for (int r = 0; r < 25; r++) {
    float d = v[r] - tau;
    if (d > 0.f) {
      int i = r * 1024 + tid;
      int slot = atomicAdd(&cnt[p], 1);
      idxb[p * NI + slot] = i;
      wgt[p * NI + slot] = d * d;
    }
  }
}

// ---------------------------------------------------------------------------
// K3: pooled[p, :768] = sum over support of w * x_vec. 8 stripes x 4 waves
// per problem; each lane owns 12 components (h=q, c=lane). atomicAdd combine.
__global__ __launch_bounds__(256) void k_pool(
    const float* __restrict__ x, const int* __restrict__ idxb,
    const float* __restrict__ wgt, const int* __restrict__ cnt,
    float* __restrict__ pooled)
{
  int p = blockIdx.x >> 3, stripe = blockIdx.x & 7;
  int b = p & 1;
  int wv = threadIdx.x >> 6, lane = threadIdx.x & 63;
  int count = cnt[p];
  float acc[12];
  #pragma unroll
  for (int q = 0; q < 12; q++) acc[q] = 0.f;
  for (int e = stripe * 4 + wv; e < count; e += 32) {
    int i = idxb[p * NI + e];
    float pw = wgt[p * NI + e];
    int t = i & 31, r = i >> 5;
    int n = r % NTOK, k = r / NTOK;
    int B = (b * TT + t) * KW + k;
    const float* xb = x + B * 150528 + n * 64 + lane;
    #pragma unroll
    for (int q = 0; q < 12; q++) acc[q] += pw * xb[q * 12544];
  }
  #pragma unroll
  for (int q = 0; q < 12; q++)
    atomicAdd(&pooled[p * 768 + q * 64 + lane], acc[q]);
}

// ---------------------------------------------------------------------------
// K4: win_raw = pooled @ win_w + win_b, then entmax-1.5 over the 11 taps per
// (p,f); store final conv weights scaled by 1/8 (the mean over f).
__global__ __launch_bounds__(384) void k_win(
    const float* __restrict__ pooled,
    const float* __restrict__ fww, const float* __restrict__ fwb,
    const float* __restrict__ bww, const float* __restrict__ bwb,
    float* __restrict__ winout)
{
  __shared__ float praw[4][88];
  int tid = threadIdx.x;
  if (tid < 352) {
    int p = tid / 88, col = tid % 88;
    const float* ww = (p >> 1) ? bww : fww;
    const float* wb = (p >> 1) ? bwb : fwb;
    float acc = wb[col];
    const float* pl = pooled + p * 768;
    #pragma unroll 8
    for (int r = 0; r < 768; r++) acc += pl[r] * ww[r * 88 + col];
    praw[p][col] = acc;
  }
  __syncthreads();
  if (tid < 32) {
    int p = tid >> 3, f = tid & 7;
    float v[11];
    float mx = -3.0e38f;
    #pragma unroll
    for (int j = 0; j < 11; j++) { v[j] = praw[p][j * 8 + f]; mx = fmaxf(mx, v[j]); }
    #pragma unroll
    for (int j = 0; j < 11; j++) v[j] = 0.5f * (v[j] - mx);
    float lo = -1.f, hi = 0.f;
    for (int it = 0; it < 30; it++) {
      float mid = 0.5f * (lo + hi);
      float s = 0.f;
      #pragma unroll
      for (int j = 0; j < 11; j++) { float d = fmaxf(v[j] - mid, 0.f); s += d * d; }
      if (s >= 1.f) lo = mid; else hi = mid;
    }
    float tau = 0.5f * (lo + hi);
    #pragma unroll
    for (int j = 0; j < 11; j++) {
      float d = fmaxf(v[j] - tau, 0.f);
      winout[p * 88 + f * 11 + j] = d * d * 0.125f;   // fold mean over f
    }
  }
}

// ---------------------------------------------------------------------------
// K5: shifted output channels 0..15. Thread = (n, cp, dir-wave, f); 32 static
// accumulators; f-reduction via shfl_xor; dir chosen per-wave (no divergence).
__global__ __launch_bounds__(256) void k_shift(
    const float* __restrict__ x, const float* __restrict__ win,
    float* __restrict__ out)
{
  int bkh = blockIdx.y;
  int b = bkh / 48, rem = bkh % 48;
  int k = rem / 12, h = rem % 12;
  int wave = threadIdx.x >> 6, lane = threadIdx.x & 63;
  int dir = wave & 1;
  int n = blockIdx.x * 2 + (wave >> 1);
  int f = lane & 7, cp = lane >> 3;
  int prob = dir * 2 + b;
  float wj[11];
  #pragma unroll
  for (int j = 0; j < 11; j++) wj[j] = win[prob * 88 + f * 11 + j];
  int base = ((b * 128 + k) * NH + h) * 12544 + n * 64 + cp * 8 + f;
  float acc[32];
  #pragma unroll
  for (int t = 0; t < 32; t++) acc[t] = 0.f;
  if (dir == 0) {
    // fwd: t_out = tp + 20 - j, tp in [0,21]
    #pragma unroll
    for (int tp = 0; tp <= 21; tp++) {
      float xv = x[base + tp * TSTRIDE];
      #pragma unroll
      for (int j = 0; j < 11; j++) {
        int to = tp + 20 - j;
        if (to >= 0 && to < 32) acc[to] += wj[j] * xv;
      }
    }
  } else {
    // bwd: t_out = tp - 10 - j, tp in [10,31]
    #pragma unroll
    for (int tp = 10; tp < 32; tp++) {
      float xv = x[base + tp * TSTRIDE];
      #pragma unroll
      for (int j = 0; j < 11; j++) {
        int to = tp - 10 - j;
        if (to >= 0 && to < 32) acc[to] += wj[j] * xv;
      }
    }
  }
  #pragma unroll
  for (int t = 0; t < 32; t++) {
    float s = acc[t];
    s += __shfl_xor(s, 1);
    s += __shfl_xor(s, 2);
    s += __shfl_xor(s, 4);
    acc[t] = s;
  }
  if (f == 0) {
    int ob = ((b * 128 + k) * NH + h) * 12544 + n * 64 + dir * 8 + cp;
    #pragma unroll
    for (int t = 0; t < 32; t++) out[ob + t * TSTRIDE] = acc[t];
  }
}

// ---------------------------------------------------------------------------
extern "C" void kernel_launch(void* const* d_in, const int* in_sizes, int n_in,
                              void* d_out, int out_size, void* d_ws, size_t ws_size,
                              hipStream_t stream)
{
  (void)in_sizes; (void)n_in; (void)out_size; (void)ws_size;
  const float* x   = (const float*)d_in[0];
  const float* fpw = (const float*)d_in[3];   // fwd_pool_w [768]
  const float* bpw = (const float*)d_in[5];   // bwd_pool_w [768]
  const float* fww = (const float*)d_in[7];   // fwd_win_w  [768*88]
  const float* fwb = (const float*)d_in[8];   // fwd_win_b  [88]
  const float* bww = (const float*)d_in[9];   // bwd_win_w  [768*88]
  const float* bwb = (const float*)d_in[10];  // bwd_win_b  [88]
  float* out = (float*)d_out;

  // workspace layout (floats): [cnt(4 int) | pooled(3072) | attn(4*NI) |
  //                             wgt(4*NI) | idx(4*NI int) | win(352)]
  float* W      = (float*)d_ws;
  int*   cnt    = (int*)W;
  float* pooled = W + 4;
  float* attn   = W + 4 + 3072;
  float* wgt    = attn + 4 * NI;
  int*   idxb   = (int*)(wgt + 4 * NI);
  float* winb   = (float*)(idxb + 4 * NI);

  hipMemsetAsync(d_ws, 0, (4 + 3072) * sizeof(float), stream);

  dim3 g1(13, 256);
  k_attn<<<g1, 256, 0, stream>>>((const float4*)x, (const float4*)fpw,
                                 (const float4*)bpw, attn, (float4*)out);
  k_entmax_big<<<4, 1024, 0, stream>>>(attn, wgt, idxb, cnt);
  k_pool<<<32, 256, 0, stream>>>(x, idxb, wgt, cnt, pooled);
  k_win<<<1, 384, 0, stream>>>(pooled, fww, fwb, bww, bwb, winb);
  dim3 g5(98, 96);
  k_shift<<<g5, 256, 0, stream>>>(x, winb, out);
}

// Round 3
// 416.978 us; speedup vs baseline: 1.0754x; 1.0754x over previous
//
#include <hip/hip_runtime.h>

// Problem constants
#define NH 12
#define NTOK 196
#define TT 32
#define KW 4
#define NI 25088            // k*n*t tokens per batch element
#define TSTRIDE 602112      // 4*12*196*64  : x flat stride for t+1 (same b,k)
// x flat index: ((B*12 + h)*196 + n)*64 + c ;  B = (b*32 + t)*4 + k

typedef float nfloat4 __attribute__((ext_vector_type(4)));

// ---------------------------------------------------------------------------
// K1: attn (fwd+bwd dot with pool weights) + write-through copy of c=16..63.
// Block 256 = 4 waves; each wave: one B, 4 consecutive n (16 lanes each = 64c).
__global__ __launch_bounds__(256) void k_attn(
    const float4* __restrict__ x4, const float4* __restrict__ wf4,
    const float4* __restrict__ wb4, float* __restrict__ attn,
    float4* __restrict__ out4)
{
  int B = blockIdx.y;
  int wave = threadIdx.x >> 6, lane = threadIdx.x & 63;
  int n = blockIdx.x * 16 + wave * 4 + (lane >> 4);
  int c4 = lane & 15;                 // float4 group: c = 4*c4
  bool nv = (n < NTOK);
  float accf = 0.f, accb = 0.f;
  #pragma unroll
  for (int h = 0; h < NH; h++) {
    float4 xv = make_float4(0.f, 0.f, 0.f, 0.f);
    int gi = ((B * NH + h) * NTOK + n) * 16 + c4;
    if (nv) xv = x4[gi];
    float4 wf = wf4[h * 16 + c4];
    float4 wb = wb4[h * 16 + c4];
    accf += xv.x * wf.x + xv.y * wf.y + xv.z * wf.z + xv.w * wf.w;
    accb += xv.x * wb.x + xv.y * wb.y + xv.z * wb.z + xv.w * wb.w;
    if (nv && c4 >= 4) {                 // pass-through channels 16..63
      nfloat4 nv4 = { xv.x, xv.y, xv.z, xv.w };
      __builtin_nontemporal_store(nv4, (nfloat4*)&out4[gi]);
    }
  }
  #pragma unroll
  for (int m = 1; m < 16; m <<= 1) {    // reduce within 16-lane (per-n) groups
    accf += __shfl_xor(accf, m);
    accb += __shfl_xor(accb, m);
  }
  if (nv && (lane & 15) == 0) {
    int b = B >> 7, t = (B >> 2) & 31, k = B & 3;
    int i = (k * NTOK + n) * TT + t;
    attn[(0 * 2 + b) * NI + i] = accf;  // prob = dir*2 + b
    attn[(1 * 2 + b) * NI + i] = accb;
  }
}

// ---------------------------------------------------------------------------
// K2: entmax-1.5 threshold tau solving g(tau)=Sum max(0,z-tau)^2 - 1 = 0.
// g is convex decreasing; Newton from tau=-1 converges monotonically (8 its).
// Then compact the support (index, weight) via atomic counter.
__global__ __launch_bounds__(1024) void k_entmax_big(
    const float* __restrict__ attn, float* __restrict__ wgt,
    int* __restrict__ idxb, int* __restrict__ cnt)
{
  int p = blockIdx.x;
  const float* a = attn + p * NI;
  int tid = threadIdx.x;
  float v[25];
  float mx = -3.0e38f;
  #pragma unroll
  for (int r = 0; r < 25; r++) {
    int i = r * 1024 + tid;
    v[r] = (i < NI) ? a[i] : -3.0e38f;
    mx = fmaxf(mx, v[r]);
  }
  __shared__ float sred1[16];
  __shared__ float sred2[16];
  __shared__ float sbc;
  int wv = tid >> 6;
  #pragma unroll
  for (int m = 1; m < 64; m <<= 1) mx = fmaxf(mx, __shfl_xor(mx, m));
  if ((tid & 63) == 0) sred1[wv] = mx;
  __syncthreads();
  if (tid == 0) {
    float m2 = sred1[0];
    for (int i2 = 1; i2 < 16; i2++) m2 = fmaxf(m2, sred1[i2]);
    sbc = m2;
  }
  __syncthreads();
  float amax = sbc;
  #pragma unroll
  for (int r = 0; r < 25; r++) v[r] = 0.5f * (v[r] - amax);
  float tau = -1.0f;
  for (int it = 0; it < 8; it++) {
    float s2 = 0.f, s1 = 0.f;
    #pragma unroll
    for (int r = 0; r < 25; r++) {
      float d = fmaxf(v[r] - tau, 0.f);
      s2 += d * d;
      s1 += d;
    }
    #pragma unroll
    for (int m = 1; m < 64; m <<= 1) {
      s2 += __shfl_xor(s2, m);
      s1 += __shfl_xor(s1, m);
    }
    if ((tid & 63) == 0) { sred2[wv] = s2; sred1[wv] = s1; }
    __syncthreads();
    if (tid == 0) {
      float S2 = 0.f, S1 = 0.f;
      for (int i2 = 0; i2 < 16; i2++) { S2 += sred2[i2]; S1 += sred1[i2]; }
      sbc = tau + (S2 - 1.f) / fmaxf(2.f * S1, 1e-12f);
    }
    __syncthreads();
    tau = sbc;
    __syncthreads();
  }
  #pragma unroll
  for (int r = 0; r < 25; r++) {
    float d = v[r] - tau;
    if (d > 0.f) {
      int i = r * 1024 + tid;
      int slot = atomicAdd(&cnt[p], 1);
      idxb[p * NI + slot] = i;
      wgt[p * NI + slot] = d * d;
    }
  }
}

// ---------------------------------------------------------------------------
// K3: pooled[p, :768] = sum over support of w * x_vec. 8 stripes x 4 waves
// per problem; each lane owns 12 components (h=q, c=lane). atomicAdd combine.
__global__ __launch_bounds__(256) void k_pool(
    const float* __restrict__ x, const int* __restrict__ idxb,
    const float* __restrict__ wgt, const int* __restrict__ cnt,
    float* __restrict__ pooled)
{
  int p = blockIdx.x >> 3, stripe = blockIdx.x & 7;
  int b = p & 1;
  int wv = threadIdx.x >> 6, lane = threadIdx.x & 63;
  int count = cnt[p];
  float acc[12];
  #pragma unroll
  for (int q = 0; q < 12; q++) acc[q] = 0.f;
  for (int e = stripe * 4 + wv; e < count; e += 32) {
    int i = idxb[p * NI + e];
    float pw = wgt[p * NI + e];
    int t = i & 31, r = i >> 5;
    int n = r % NTOK, k = r / NTOK;
    int B = (b * TT + t) * KW + k;
    const float* xb = x + B * 150528 + n * 64 + lane;
    #pragma unroll
    for (int q = 0; q < 12; q++) acc[q] += pw * xb[q * 12544];
  }
  #pragma unroll
  for (int q = 0; q < 12; q++)
    atomicAdd(&pooled[p * 768 + q * 64 + lane], acc[q]);
}

// ---------------------------------------------------------------------------
// K4: win_raw = pooled @ win_w + win_b, then entmax-1.5 over the 11 taps per
// (p,f); store final conv weights scaled by 1/8 (the mean over f).
__global__ __launch_bounds__(384) void k_win(
    const float* __restrict__ pooled,
    const float* __restrict__ fww, const float* __restrict__ fwb,
    const float* __restrict__ bww, const float* __restrict__ bwb,
    float* __restrict__ winout)
{
  __shared__ float praw[4][88];
  int tid = threadIdx.x;
  if (tid < 352) {
    int p = tid / 88, col = tid % 88;
    const float* ww = (p >> 1) ? bww : fww;
    const float* wb = (p >> 1) ? bwb : fwb;
    float acc = wb[col];
    const float* pl = pooled + p * 768;
    #pragma unroll 8
    for (int r = 0; r < 768; r++) acc += pl[r] * ww[r * 88 + col];
    praw[p][col] = acc;
  }
  __syncthreads();
  if (tid < 32) {
    int p = tid >> 3, f = tid & 7;
    float v[11];
    float mx = -3.0e38f;
    #pragma unroll
    for (int j = 0; j < 11; j++) { v[j] = praw[p][j * 8 + f]; mx = fmaxf(mx, v[j]); }
    #pragma unroll
    for (int j = 0; j < 11; j++) v[j] = 0.5f * (v[j] - mx);
    float lo = -1.f, hi = 0.f;
    for (int it = 0; it < 30; it++) {
      float mid = 0.5f * (lo + hi);
      float s = 0.f;
      #pragma unroll
      for (int j = 0; j < 11; j++) { float d = fmaxf(v[j] - mid, 0.f); s += d * d; }
      if (s >= 1.f) lo = mid; else hi = mid;
    }
    float tau = 0.5f * (lo + hi);
    #pragma unroll
    for (int j = 0; j < 11; j++) {
      float d = fmaxf(v[j] - tau, 0.f);
      winout[p * 88 + f * 11 + j] = d * d * 0.125f;   // fold mean over f
    }
  }
}

// ---------------------------------------------------------------------------
// K5: shifted output channels 0..15, fwd+bwd fused: x[t] held in registers,
// read ONCE per element. Wave = one (n); lanes = (cp,f). f-reduce via shfl.
__global__ __launch_bounds__(256) void k_shift(
    const float* __restrict__ x, const float* __restrict__ win,
    float* __restrict__ out)
{
  int bkh = blockIdx.y;               // 96 = b*48 + k*12 + h
  int b = bkh / 48, rem = bkh % 48;
  int k = rem / 12, h = rem % 12;
  int wave = threadIdx.x >> 6, lane = threadIdx.x & 63;
  int n = blockIdx.x * 4 + wave;      // grid.x = 49, 49*4 = 196 exact
  int f = lane & 7, cp = lane >> 3;
  float wjf[11], wjb[11];
  #pragma unroll
  for (int j = 0; j < 11; j++) {
    wjf[j] = win[(0 * 2 + b) * 88 + f * 11 + j];
    wjb[j] = win[(1 * 2 + b) * 88 + f * 11 + j];
  }
  int base = ((b * 128 + k) * NH + h) * 12544 + n * 64 + cp * 8 + f;
  float xr[32];
  #pragma unroll
  for (int tp = 0; tp < 32; tp++) xr[tp] = x[base + tp * TSTRIDE];

  int ob = ((b * 128 + k) * NH + h) * 12544 + n * 64 + cp;
  float acc[32];

  // fwd: t_out = tp + 20 - j, valid tp in [0,21]
  #pragma unroll
  for (int t = 0; t < 32; t++) acc[t] = 0.f;
  #pragma unroll
  for (int tp = 0; tp <= 21; tp++) {
    #pragma unroll
    for (int j = 0; j < 11; j++) {
      int to = tp + 20 - j;
      if (to >= 0 && to < 32) acc[to] += wjf[j] * xr[tp];
    }
  }
  #pragma unroll
  for (int t = 0; t < 32; t++) {
    float s = acc[t];
    s += __shfl_xor(s, 1);
    s += __shfl_xor(s, 2);
    s += __shfl_xor(s, 4);
    acc[t] = s;
  }
  if (f == 0) {
    #pragma unroll
    for (int t = 0; t < 32; t++)
      __builtin_nontemporal_store(acc[t], &out[ob + t * TSTRIDE]);
  }

  // bwd: t_out = tp - 10 - j, valid tp in [10,31]
  #pragma unroll
  for (int t = 0; t < 32; t++) acc[t] = 0.f;
  #pragma unroll
  for (int tp = 10; tp < 32; tp++) {
    #pragma unroll
    for (int j = 0; j < 11; j++) {
      int to = tp - 10 - j;
      if (to >= 0 && to < 32) acc[to] += wjb[j] * xr[tp];
    }
  }
  #pragma unroll
  for (int t = 0; t < 32; t++) {
    float s = acc[t];
    s += __shfl_xor(s, 1);
    s += __shfl_xor(s, 2);
    s += __shfl_xor(s, 4);
    acc[t] = s;
  }
  if (f == 0) {
    #pragma unroll
    for (int t = 0; t < 32; t++)
      __builtin_nontemporal_store(acc[t], &out[ob + 8 + t * TSTRIDE]);
  }
}

// ---------------------------------------------------------------------------
extern "C" void kernel_launch(void* const* d_in, const int* in_sizes, int n_in,
                              void* d_out, int out_size, void* d_ws, size_t ws_size,
                              hipStream_t stream)
{
  (void)in_sizes; (void)n_in; (void)out_size; (void)ws_size;
  const float* x   = (const float*)d_in[0];
  const float* fpw = (const float*)d_in[3];   // fwd_pool_w [768]
  const float* bpw = (const float*)d_in[5];   // bwd_pool_w [768]
  const float* fww = (const float*)d_in[7];   // fwd_win_w  [768*88]
  const float* fwb = (const float*)d_in[8];   // fwd_win_b  [88]
  const float* bww = (const float*)d_in[9];   // bwd_win_w  [768*88]
  const float* bwb = (const float*)d_in[10];  // bwd_win_b  [88]
  float* out = (float*)d_out;

  // workspace layout (floats): [cnt(4 int) | pooled(3072) | attn(4*NI) |
  //                             wgt(4*NI) | idx(4*NI int) | win(352)]
  float* W      = (float*)d_ws;
  int*   cnt    = (int*)W;
  float* pooled = W + 4;
  float* attn   = W + 4 + 3072;
  float* wgt    = attn + 4 * NI;
  int*   idxb   = (int*)(wgt + 4 * NI);
  float* winb   = (float*)(idxb + 4 * NI);

  (void)hipMemsetAsync(d_ws, 0, (4 + 3072) * sizeof(float), stream);

  dim3 g1(13, 256);
  k_attn<<<g1, 256, 0, stream>>>((const float4*)x, (const float4*)fpw,
                                 (const float4*)bpw, attn, (float4*)out);
  k_entmax_big<<<4, 1024, 0, stream>>>(attn, wgt, idxb, cnt);
  k_pool<<<32, 256, 0, stream>>>(x, idxb, wgt, cnt, pooled);
  k_win<<<1, 384, 0, stream>>>(pooled, fww, fwb, bww, bwb, winb);
  dim3 g5(49, 96);
  k_shift<<<g5, 256, 0, stream>>>(x, winb, out);
}